// Round 9
// baseline (12253.123 us; speedup 1.0000x reference)
//
#include <hip/hip_runtime.h>

#define TSTEPS 50
#define NB (2048 * 256)   // floats per h half-plane (256 rows x 2048 seqs)

__device__ __forceinline__ float sigm(float x) { return 1.0f / (1.0f + expf(-x)); }
__device__ __forceinline__ float gelu_t(float x) {
  float x3 = x * x * x;
  return 0.5f * x * (1.0f + tanhf(0.7978845608028654f * (x + 0.044715f * x3)));
}

// za[m][g] += a[m] * w[g]  (2 seqs x 4 gates = 8 FMA). Inline function, not a
// macro: macro params collided with .x/.y/.z/.w member tokens twice (R5, R7).
__device__ __forceinline__ void fma8(float (&za)[2][4], const float2 a, const float4 w) {
  za[0][0] += a.x * w.x; za[0][1] += a.x * w.y; za[0][2] += a.x * w.z; za[0][3] += a.x * w.w;
  za[1][0] += a.y * w.x; za[1][1] += a.y * w.y; za[1][2] += a.y * w.z; za[1][3] += a.y * w.w;
}

// m-group barrier (16 blocks, all on one XCD since blk%8 == mg%8).
// Plain __threadfence pair: empirically correct (R1-R4) and L2-friendly (R4:
// FETCH stayed 230MB). Do NOT hand-roll cache ops (R6: buffer_inv sc0 -> 4.4GB).
__device__ __forceinline__ void mg_barrier(unsigned* bar, unsigned target) {
  __syncthreads();
  if (threadIdx.x == 0) {
    __threadfence();
    atomicAdd(bar, 1u);
    while (atomicAdd(bar, 0u) < target) __builtin_amdgcn_s_sleep(4);
    __threadfence();
  }
  __syncthreads();
}

// Pack W per-jcol streams: Wp1[jcol][k=0..271][4 gates], Wp2[jcol][k=0..511][4].
__global__ void __launch_bounds__(256)
pack_w(const float* __restrict__ Wx1, const float* __restrict__ Wh1,
       const float* __restrict__ Wx2, const float* __restrict__ Wh2,
       float* __restrict__ Wp1, float* __restrict__ Wp2, unsigned* __restrict__ bar) {
  const int idx = blockIdx.x * 256 + threadIdx.x;
  if (blockIdx.x == 0 && threadIdx.x < 256) bar[threadIdx.x] = 0u;
  if (idx < 256 * 272 * 4) {
    int g = idx & 3, k = (idx >> 2) % 272, jcol = idx / (272 * 4);
    int col = (g << 8) + jcol;
    Wp1[idx] = (k < 16) ? Wx1[(k << 10) + col] : Wh1[((k - 16) << 10) + col];
  }
  if (idx < 256 * 512 * 4) {
    int g = idx & 3, k = (idx >> 2) & 511, jcol = idx >> 11;
    int col = (g << 8) + jcol;
    Wp2[idx] = (k < 256) ? Wx2[(k << 10) + col] : Wh2[((k - 256) << 10) + col];
  }
}

// x[seq][t*16+d] -> xT[t*16+d][seq]
__global__ void __launch_bounds__(256)
transpose_x(const float* __restrict__ x, float* __restrict__ xT) {
  __shared__ float Ts[64][65];
  const int st = blockIdx.x & 31;
  const int tt = blockIdx.x >> 5;
  const int s0 = st << 6, t0 = tt << 6;
  const int r = threadIdx.x >> 6;
  const int c = threadIdx.x & 63;
  #pragma unroll
  for (int i = 0; i < 16; ++i) {
    int row = r + (i << 2);
    int td = t0 + c;
    if (td < 800) Ts[row][c] = x[(s0 + row) * 800 + td];
  }
  __syncthreads();
  #pragma unroll
  for (int i = 0; i < 16; ++i) {
    int row = r + (i << 2);
    int td = t0 + row;
    if (td < 800) xT[td * 2048 + s0 + c] = Ts[c][row];
  }
}

// Persistent fused 2-layer LSTM + time-mean pool.
// grid 256 = 16 mg (128 seqs, XCD-aligned: blk&15, XCD=blk%8=mg%8) x 16 jg.
// block 1024 = 16 waves (1 block/CU, 4 waves/SIMD); wave wv owns ONE hidden col
// jcol = jg*16+wv (lanes = 128 seqs, 2/lane) -> W rows are wave-uniform (scalar
// path, zero vector traffic). A staged in 32KB LDS double-buffer.
// Phase p: x[p] -> z1; h1[p-1] -> z1 (W1h) AND z2 (W2x) dual-use; h2[p-2] -> z2.
// COOPERATIVE GRID MUST BE <= 256 (R8: grid 512 silently refused to launch).
__global__ void __launch_bounds__(1024, 1)
lstm_fused(const float* __restrict__ xT,
           const float* __restrict__ Wp1, const float* __restrict__ Wp2,
           const float* __restrict__ b1, const float* __restrict__ b2,
           float* __restrict__ pair0, float* __restrict__ pair1,
           float* __restrict__ xg, unsigned* __restrict__ bar)
{
  __shared__ float As[2][32 * 128];        // 2 x 16KB chunk buffers [k][128 seqs]

  const int tid = threadIdx.x;
  const int lane = tid & 63;
  const int wv = __builtin_amdgcn_readfirstlane(tid >> 6);   // 0..15, uniform
  const int blk = blockIdx.x;
  const int mg = blk & 15, jg = blk >> 4;  // jg 0..15
  const int mgoff = mg << 7;               // 128 seqs
  const int jcol = (jg << 4) + wv;         // 0..255, wave-uniform
  unsigned* mybar = bar + (mg << 4);

  const float* wp1 = Wp1 + (size_t)jcol * (272 * 4);
  const float* wp2 = Wp2 + (size_t)jcol * (512 * 4);

  float4 zb1, zb2;
  #pragma unroll
  for (int g = 0; g < 4; ++g) {
    (&zb1.x)[g] = b1[(g << 8) + jcol];
    (&zb2.x)[g] = b2[(g << 8) + jcol];
  }

  float c1[2] = {0, 0}, c2[2] = {0, 0}, pool[2] = {0, 0};
  float z1[2][4], z2[2][4];
  float* const pr[2] = { pair0, pair1 };

  const int srow = tid >> 5;               // 0..31
  const int scol = (tid & 31) << 2;        // 0..124

  auto stage32 = [&](const float* base, float4& S) {
    S = *(const float4*)(base + (size_t)srow * 2048 + scol);
  };
  auto dswr32 = [&](float* buf, const float4& S) {
    *(float4*)(buf + (srow << 7) + scol) = S;   // contiguous b128: conflict-free
  };
  auto stage16 = [&](const float* base, float4& S) {
    if (srow < 16) S = *(const float4*)(base + (size_t)srow * 2048 + scol);
  };
  auto dswr16 = [&](float* buf, const float4& S) {
    if (srow < 16) *(float4*)(buf + (srow << 7) + scol) = S;
  };

  const int aoff = lane << 1;
  auto consume_x = [&](const float* buf) {           // 16 k-rows -> z1 (W1x)
    float2 Aq[4];
    #pragma unroll
    for (int i = 0; i < 4; ++i) Aq[i] = *(const float2*)(buf + (i << 7) + aoff);
    #pragma unroll
    for (int k = 0; k < 16; ++k) {
      float2 a = Aq[k & 3];
      float4 w = *(const float4*)(wp1 + (k << 2));
      fma8(z1, a, w);
      int kn = k + 4; kn = kn > 15 ? 15 : kn;
      Aq[k & 3] = *(const float2*)(buf + (kn << 7) + aoff);
    }
  };
  auto consume_dual = [&](const float* buf, int kk0) {  // h1 rows kk0..+31 -> z1,z2
    const float* w1b = wp1 + ((16 + kk0) << 2);
    const float* w2b = wp2 + (kk0 << 2);
    float2 Aq[4];
    #pragma unroll
    for (int i = 0; i < 4; ++i) Aq[i] = *(const float2*)(buf + (i << 7) + aoff);
    #pragma unroll
    for (int k = 0; k < 32; ++k) {
      float2 a = Aq[k & 3];
      float4 wva = *(const float4*)(w1b + (k << 2));
      float4 wvb = *(const float4*)(w2b + (k << 2));
      fma8(z1, a, wva);
      fma8(z2, a, wvb);
      int kn = k + 4; kn = kn > 31 ? 31 : kn;
      Aq[k & 3] = *(const float2*)(buf + (kn << 7) + aoff);
    }
  };
  auto consume_w2 = [&](const float* buf, int koff) {   // 32 k-rows -> z2 only
    const float* w2b = wp2 + (koff << 2);
    float2 Aq[4];
    #pragma unroll
    for (int i = 0; i < 4; ++i) Aq[i] = *(const float2*)(buf + (i << 7) + aoff);
    #pragma unroll
    for (int k = 0; k < 32; ++k) {
      float2 a = Aq[k & 3];
      float4 w = *(const float4*)(w2b + (k << 2));
      fma8(z2, a, w);
      int kn = k + 4; kn = kn > 31 ? 31 : kn;
      Aq[k & 3] = *(const float2*)(buf + (kn << 7) + aoff);
    }
  };

  for (int p = 0; p <= TSTEPS; ++p) {
    float* const pw = pr[p & 1];
    const float* const prd = pr[(p + 1) & 1];
    const bool doL1 = (p < TSTEPS);
    const bool doL2 = (p >= 1);
    const bool doH2 = (p >= 2);

    // chunk plan: type 0=x(z1) 1=dual(z1,z2) 2=h1->z2 only 3=h2->z2
    const float* csrc[17]; int ctyp[17], ckk[17]; int nc = 0;
    if (doL1) { csrc[nc] = xT + (size_t)(p << 4) * 2048 + mgoff; ctyp[nc] = 0; ckk[nc] = 0; ++nc; }
    if (doL2) {
      for (int i = 0; i < 8; ++i) {
        csrc[nc] = prd + (size_t)(i << 5) * 2048 + mgoff;
        ctyp[nc] = doL1 ? 1 : 2; ckk[nc] = i << 5; ++nc;
      }
    }
    if (doH2) {
      for (int i = 0; i < 8; ++i) {
        csrc[nc] = prd + (size_t)(256 + (i << 5)) * 2048 + mgoff;
        ctyp[nc] = 3; ckk[nc] = i << 5; ++nc;
      }
    }

    if (doL1) {
      #pragma unroll
      for (int m = 0; m < 2; ++m) {
        z1[m][0] = zb1.x; z1[m][1] = zb1.y; z1[m][2] = zb1.z; z1[m][3] = zb1.w;
      }
    }
    if (doL2) {
      #pragma unroll
      for (int m = 0; m < 2; ++m) {
        z2[m][0] = zb2.x; z2[m][1] = zb2.y; z2[m][2] = zb2.z; z2[m][3] = zb2.w;
      }
    }

    // T14 pipelined chunk loop: issue next-chunk loads early, ds_write late
    float4 S;
    if (ctyp[0] == 0) { stage16(csrc[0], S); dswr16(As[0], S); }
    else              { stage32(csrc[0], S); dswr32(As[0], S); }
    __syncthreads();
    int cur = 0;
    for (int c = 0; c < nc; ++c) {
      if (c + 1 < nc) {
        if (ctyp[c + 1] == 0) stage16(csrc[c + 1], S); else stage32(csrc[c + 1], S);
      }
      const float* buf = As[cur];
      switch (ctyp[c]) {
        case 0: consume_x(buf); break;
        case 1: consume_dual(buf, ckk[c]); break;
        case 2: consume_w2(buf, ckk[c]); break;
        case 3: consume_w2(buf, 256 + ckk[c]); break;
      }
      if (c + 1 < nc) {
        if (ctyp[c + 1] == 0) dswr16(As[cur ^ 1], S); else dswr32(As[cur ^ 1], S);
        cur ^= 1;
      }
      __syncthreads();
    }

    // epilogues
    if (doL1) {
      float2 hv;
      #pragma unroll
      for (int m = 0; m < 2; ++m) {
        float iv = sigm(z1[m][0]), fv = sigm(z1[m][1]);
        float gv = tanhf(z1[m][2]), ov = sigm(z1[m][3]);
        c1[m] = fv * c1[m] + iv * gv;
        (&hv.x)[m] = ov * tanhf(c1[m]);
      }
      *(float2*)(pw + (size_t)jcol * 2048 + mgoff + (lane << 1)) = hv;
    }
    if (doL2) {
      float2 hv;
      #pragma unroll
      for (int m = 0; m < 2; ++m) {
        float iv = sigm(z2[m][0]), fv = sigm(z2[m][1]);
        float gv = tanhf(z2[m][2]), ov = sigm(z2[m][3]);
        c2[m] = fv * c2[m] + iv * gv;
        float h = ov * tanhf(c2[m]);
        pool[m] += h;
        (&hv.x)[m] = h;
      }
      *(float2*)(pw + (size_t)(256 + jcol) * 2048 + mgoff + (lane << 1)) = hv;
    }

    if (p < TSTEPS) mg_barrier(mybar, (unsigned)(p + 1) * 16u);
  }

  #pragma unroll
  for (int m = 0; m < 2; ++m)
    xg[(size_t)(mgoff + (lane << 1) + m) * 256 + jcol] = pool[m] * (1.0f / 50.0f);
}

// ---- GAT (verified R1-R6) ---------------------------------------------------
__global__ void __launch_bounds__(256)
gat_feat(const float* __restrict__ xin, const float* __restrict__ gW,
         const float* __restrict__ a_src, const float* __restrict__ a_dst,
         float* __restrict__ hfeat, float* __restrict__ es, float* __restrict__ ed)
{
  __shared__ float Xs[8][260];
  const int tid = threadIdx.x;
  const int r0 = blockIdx.x << 3;
  #pragma unroll
  for (int i = 0; i < 8; ++i) Xs[i][tid] = xin[((r0 + i) << 8) + tid];
  __syncthreads();
  float acc[8];
  #pragma unroll
  for (int i = 0; i < 8; ++i) acc[i] = 0.0f;
  for (int k = 0; k < 256; k += 4) {
    const float w0 = gW[(k + 0) * 256 + tid];
    const float w1 = gW[(k + 1) * 256 + tid];
    const float w2 = gW[(k + 2) * 256 + tid];
    const float w3 = gW[(k + 3) * 256 + tid];
    #pragma unroll
    for (int i = 0; i < 8; ++i)
      acc[i] += Xs[i][k] * w0 + Xs[i][k + 1] * w1 + Xs[i][k + 2] * w2 + Xs[i][k + 3] * w3;
  }
  const int h = tid >> 6;
  const int lane = tid & 63;
  const float asv = a_src[(h << 6) + lane];
  const float adv = a_dst[(h << 6) + lane];
  #pragma unroll
  for (int i = 0; i < 8; ++i) {
    hfeat[((r0 + i) << 8) + tid] = acc[i];
    float pse = acc[i] * asv;
    float pde = acc[i] * adv;
    #pragma unroll
    for (int off = 32; off > 0; off >>= 1) {
      pse += __shfl_down(pse, off);
      pde += __shfl_down(pde, off);
    }
    if (lane == 0) {
      es[((r0 + i) << 2) + h] = pse;
      ed[((r0 + i) << 2) + h] = pde;
    }
  }
}

__global__ void __launch_bounds__(256)
gat_out(const float* __restrict__ hfeat, const float* __restrict__ es, const float* __restrict__ ed,
        const float* __restrict__ gb, float* __restrict__ yout)
{
  __shared__ float exs[32][4];
  __shared__ float invden[4];
  const int tid = threadIdx.x;
  const int rbase = blockIdx.x << 5;
  if (tid < 128) {
    const int u = tid >> 2, h = tid & 3;
    float l = es[((rbase + u) << 2) + h] + ed[(rbase << 2) + h];
    exs[u][h] = (l < 0.0f) ? 0.2f * l : l;
  }
  __syncthreads();
  if (tid < 4) {
    const int h = tid;
    float m = -1e30f;
    for (int u = 0; u < 32; ++u) m = fmaxf(m, exs[u][h]);
    float s = 0.0f;
    for (int u = 0; u < 32; ++u) { float e = expf(exs[u][h] - m); exs[u][h] = e; s += e; }
    s += exs[0][h];                        // duplicate 0->0 edge
    invden[h] = 1.0f / (s + 1e-9f);
  }
  __syncthreads();
  const int h = tid >> 6;
  const float h0 = hfeat[(rbase << 8) + tid];
  float s = exs[0][h] * h0;
  for (int u = 0; u < 32; ++u)
    s += exs[u][h] * hfeat[((rbase + u) << 8) + tid];
  const float bias = gb[tid];
  const float inv1 = 1.0f / (1.0f + 1e-9f);
  yout[(rbase << 8) + tid] = gelu_t(s * invden[h] + bias);
  const float gv = gelu_t(h0 * inv1 + bias);
  for (int v = 1; v < 32; ++v)
    yout[((rbase + v) << 8) + tid] = gv;
}

// ---- launch -----------------------------------------------------------------
extern "C" void kernel_launch(void* const* d_in, const int* in_sizes, int n_in,
                              void* d_out, int out_size, void* d_ws, size_t ws_size,
                              hipStream_t stream) {
  (void)in_sizes; (void)n_in; (void)out_size; (void)ws_size;
  const float* states = (const float*)d_in[0];
  const float* Wx1 = (const float*)d_in[1];
  const float* Wh1 = (const float*)d_in[2];
  const float* b1  = (const float*)d_in[3];
  const float* Wx2 = (const float*)d_in[4];
  const float* Wh2 = (const float*)d_in[5];
  const float* b2  = (const float*)d_in[6];
  const float* gW1 = (const float*)d_in[7];
  const float* gas1 = (const float*)d_in[8];
  const float* gad1 = (const float*)d_in[9];
  const float* gb1 = (const float*)d_in[10];
  const float* gW2 = (const float*)d_in[11];
  const float* gas2 = (const float*)d_in[12];
  const float* gad2 = (const float*)d_in[13];
  const float* gb2 = (const float*)d_in[14];

  float* ws = (float*)d_ws;
  float* pair0 = ws;                       // 2*NB floats (h1|h2 plane)
  float* pair1 = ws + 2 * (size_t)NB;      // 2*NB floats
  float* xg    = ws + 4 * (size_t)NB;      // NB floats
  float* xT    = ws + 5 * (size_t)NB;      // 800*2048 floats
  float* Wp1   = xT + 800 * 2048;          // 256*272*4 = 278528
  float* Wp2   = Wp1 + 278528;             // 256*512*4 = 524288
  unsigned* bar = (unsigned*)(Wp2 + 524288);
  // GAT aliases (pair buffers dead after lstm)
  float* y1    = pair0;
  float* hfeat = pair0 + NB;
  float* es    = pair1;
  float* ed    = pair1 + 2048 * 4;
  float* dout  = (float*)d_out;

  pack_w<<<dim3(2048), dim3(256), 0, stream>>>(Wx1, Wh1, Wx2, Wh2, Wp1, Wp2, bar);
  transpose_x<<<dim3(32 * 13), dim3(256), 0, stream>>>(states, xT);

  void* args[] = { (void*)&xT, (void*)&Wp1, (void*)&Wp2, (void*)&b1, (void*)&b2,
                   (void*)&pair0, (void*)&pair1, (void*)&xg, (void*)&bar };
  hipError_t err = hipLaunchCooperativeKernel((void*)lstm_fused, dim3(256), dim3(1024),
                                              args, 0, stream);
  if (err != hipSuccess) {
    // Fallback: grid == 1 block/CU capacity, so a plain launch is co-resident
    // anyway. NEVER silently drop the launch (R8: zero-output failure).
    lstm_fused<<<dim3(256), dim3(1024), 0, stream>>>(xT, Wp1, Wp2, b1, b2,
                                                     pair0, pair1, xg, bar);
  }

  gat_feat<<<dim3(256), dim3(256), 0, stream>>>(xg, gW1, gas1, gad1, hfeat, es, ed);
  gat_out<<<dim3(64), dim3(256), 0, stream>>>(hfeat, es, ed, gb1, y1);
  gat_feat<<<dim3(256), dim3(256), 0, stream>>>(y1, gW2, gas2, gad2, hfeat, es, ed);
  gat_out<<<dim3(64), dim3(256), 0, stream>>>(hfeat, es, ed, gb2, dout);
}

// Round 10
// 2925.762 us; speedup vs baseline: 4.1880x; 4.1880x over previous
//
#include <hip/hip_runtime.h>

#define TSTEPS 50
#define NB (2048 * 256)   // floats per h half-plane (256 rows x 2048 seqs)

__device__ __forceinline__ float sigm(float x) { return 1.0f / (1.0f + expf(-x)); }
__device__ __forceinline__ float gelu_t(float x) {
  float x3 = x * x * x;
  return 0.5f * x * (1.0f + tanhf(0.7978845608028654f * (x + 0.044715f * x3)));
}

// za[m][g] += a[m] * w[g]. Inline fn, not macro (macro param/member collisions R5,R7).
__device__ __forceinline__ void fma8(float (&za)[2][4], const float2 a, const float4 w) {
  za[0][0] += a.x * w.x; za[0][1] += a.x * w.y; za[0][2] += a.x * w.z; za[0][3] += a.x * w.w;
  za[1][0] += a.y * w.x; za[1][1] += a.y * w.y; za[1][2] += a.y * w.z; za[1][3] += a.y * w.w;
}

// m-group barrier (16 blocks, one XCD: blk%8==mg%8). Plain __threadfence pair
// only (R4-proven). NO hand-rolled cache ops (R6), NO runtime-indexed local
// arrays anywhere in the kernel (R9: 34GB scratch traffic — guide rule #20).
__device__ __forceinline__ void mg_barrier(unsigned* bar, unsigned target) {
  __syncthreads();
  if (threadIdx.x == 0) {
    __threadfence();
    atomicAdd(bar, 1u);
    while (atomicAdd(bar, 0u) < target) __builtin_amdgcn_s_sleep(4);
    __threadfence();
  }
  __syncthreads();
}

// Pack W per-jcol streams: Wp1[jcol][k=0..271][4 gates], Wp2[jcol][k=0..511][4].
__global__ void __launch_bounds__(256)
pack_w(const float* __restrict__ Wx1, const float* __restrict__ Wh1,
       const float* __restrict__ Wx2, const float* __restrict__ Wh2,
       float* __restrict__ Wp1, float* __restrict__ Wp2, unsigned* __restrict__ bar) {
  const int idx = blockIdx.x * 256 + threadIdx.x;
  if (blockIdx.x == 0 && threadIdx.x < 256) bar[threadIdx.x] = 0u;
  if (idx < 256 * 272 * 4) {
    int g = idx & 3, k = (idx >> 2) % 272, jcol = idx / (272 * 4);
    int col = (g << 8) + jcol;
    Wp1[idx] = (k < 16) ? Wx1[(k << 10) + col] : Wh1[((k - 16) << 10) + col];
  }
  if (idx < 256 * 512 * 4) {
    int g = idx & 3, k = (idx >> 2) & 511, jcol = idx >> 11;
    int col = (g << 8) + jcol;
    Wp2[idx] = (k < 256) ? Wx2[(k << 10) + col] : Wh2[((k - 256) << 10) + col];
  }
}

// x[seq][t*16+d] -> xT[t*16+d][seq]
__global__ void __launch_bounds__(256)
transpose_x(const float* __restrict__ x, float* __restrict__ xT) {
  __shared__ float Ts[64][65];
  const int st = blockIdx.x & 31;
  const int tt = blockIdx.x >> 5;
  const int s0 = st << 6, t0 = tt << 6;
  const int r = threadIdx.x >> 6;
  const int c = threadIdx.x & 63;
  #pragma unroll
  for (int i = 0; i < 16; ++i) {
    int row = r + (i << 2);
    int td = t0 + c;
    if (td < 800) Ts[row][c] = x[(s0 + row) * 800 + td];
  }
  __syncthreads();
  #pragma unroll
  for (int i = 0; i < 16; ++i) {
    int row = r + (i << 2);
    int td = t0 + row;
    if (td < 800) xT[td * 2048 + s0 + c] = Ts[c][row];
  }
}

// Persistent fused 2-layer LSTM + time-mean pool.
// grid 256 = 16 mg (128 seqs, XCD-aligned) x 16 jg; block 1024 = 16 waves
// (4 waves/SIMD); wave wv owns jcol = jg*16+wv -> W wave-uniform streams.
// A staged in 32KB LDS double-buffer, 32-row chunks. Chunk plan computed
// ARITHMETICALLY (no local arrays): chunk i covers h rows 32*i (works for
// both h1 i<8 and h2 i>=8 since 256+(i-8)*32 == 32*i), W2 offset = 32*i.
__global__ void __launch_bounds__(1024, 1)
lstm_fused(const float* __restrict__ xT,
           const float* __restrict__ Wp1, const float* __restrict__ Wp2,
           const float* __restrict__ b1, const float* __restrict__ b2,
           float* __restrict__ pair0, float* __restrict__ pair1,
           float* __restrict__ xg, unsigned* __restrict__ bar)
{
  __shared__ float As0[32 * 128];
  __shared__ float As1[32 * 128];

  const int tid = threadIdx.x;
  const int lane = tid & 63;
  const int wv = __builtin_amdgcn_readfirstlane(tid >> 6);   // 0..15, uniform
  const int blk = blockIdx.x;
  const int mg = blk & 15, jg = blk >> 4;
  const int mgoff = mg << 7;               // 128 seqs
  const int jcol = (jg << 4) + wv;         // 0..255, wave-uniform
  unsigned* mybar = bar + (mg << 4);

  const float* wp1 = Wp1 + (size_t)jcol * (272 * 4);
  const float* wp2 = Wp2 + (size_t)jcol * (512 * 4);

  float4 zb1, zb2;
  #pragma unroll
  for (int g = 0; g < 4; ++g) {
    (&zb1.x)[g] = b1[(g << 8) + jcol];
    (&zb2.x)[g] = b2[(g << 8) + jcol];
  }

  float c1[2] = {0, 0}, c2[2] = {0, 0}, pool[2] = {0, 0};
  float z1[2][4], z2[2][4];

  const int srow = tid >> 5;               // 0..31
  const int scol = (tid & 31) << 2;        // 0..124 (floats)

  const int aoff = lane << 1;
  auto consume_x = [&](const float* buf) {           // 16 k-rows -> z1 (W1x)
    float2 Aq[4];
    #pragma unroll
    for (int i = 0; i < 4; ++i) Aq[i] = *(const float2*)(buf + (i << 7) + aoff);
    #pragma unroll
    for (int k = 0; k < 16; ++k) {
      float2 a = Aq[k & 3];
      float4 w = *(const float4*)(wp1 + (k << 2));
      fma8(z1, a, w);
      int kn = k + 4; kn = kn > 15 ? 15 : kn;
      Aq[k & 3] = *(const float2*)(buf + (kn << 7) + aoff);
    }
  };
  auto consume_dual = [&](const float* buf, int kk0) {  // h1 rows kk0..+31 -> z1,z2
    const float* w1b = wp1 + ((16 + kk0) << 2);
    const float* w2b = wp2 + (kk0 << 2);
    float2 Aq[4];
    #pragma unroll
    for (int i = 0; i < 4; ++i) Aq[i] = *(const float2*)(buf + (i << 7) + aoff);
    #pragma unroll
    for (int k = 0; k < 32; ++k) {
      float2 a = Aq[k & 3];
      float4 wva = *(const float4*)(w1b + (k << 2));
      float4 wvb = *(const float4*)(w2b + (k << 2));
      fma8(z1, a, wva);
      fma8(z2, a, wvb);
      int kn = k + 4; kn = kn > 31 ? 31 : kn;
      Aq[k & 3] = *(const float2*)(buf + (kn << 7) + aoff);
    }
  };
  auto consume_w2 = [&](const float* buf, int koff) {   // 32 k-rows -> z2 only
    const float* w2b = wp2 + (koff << 2);
    float2 Aq[4];
    #pragma unroll
    for (int i = 0; i < 4; ++i) Aq[i] = *(const float2*)(buf + (i << 7) + aoff);
    #pragma unroll
    for (int k = 0; k < 32; ++k) {
      float2 a = Aq[k & 3];
      float4 w = *(const float4*)(w2b + (k << 2));
      fma8(z2, a, w);
      int kn = k + 4; kn = kn > 31 ? 31 : kn;
      Aq[k & 3] = *(const float2*)(buf + (kn << 7) + aoff);
    }
  };

  for (int p = 0; p <= TSTEPS; ++p) {
    float* const pw = (p & 1) ? pair1 : pair0;
    const float* const prd = (p & 1) ? pair0 : pair1;
    const bool doL1 = (p < TSTEPS);
    const bool doL2 = (p >= 1);
    const bool doH2 = (p >= 2);
    const int cL1 = doL1 ? 1 : 0;
    const int nc = cL1 + (doL2 ? 8 : 0) + (doH2 ? 8 : 0);
    const float* const xsrc = xT + (size_t)(p << 4) * 2048 + mgoff;

    // chunk c source, computed in registers (c>=cL1: h rows 32*(c-cL1))
    auto chunk_base = [&](int c) -> const float* {
      if (doL1 && c == 0) return xsrc;
      return prd + ((size_t)(c - cL1) << 5) * 2048 + mgoff;
    };

    if (doL1) {
      #pragma unroll
      for (int m = 0; m < 2; ++m) {
        z1[m][0] = zb1.x; z1[m][1] = zb1.y; z1[m][2] = zb1.z; z1[m][3] = zb1.w;
      }
    }
    if (doL2) {
      #pragma unroll
      for (int m = 0; m < 2; ++m) {
        z2[m][0] = zb2.x; z2[m][1] = zb2.y; z2[m][2] = zb2.z; z2[m][3] = zb2.w;
      }
    }

    // T14 pipelined chunk loop (stage early, ds_write late). Chunk 0 may be
    // the 16-row x chunk; all chunks >=1 are 32-row h chunks.
    float4 S;
    {
      const float* b0 = chunk_base(0);
      if (doL1) {            // x chunk: 16 rows
        if (srow < 16) S = *(const float4*)(b0 + (size_t)srow * 2048 + scol);
        __syncthreads();     // (no-op ordering; keeps pattern uniform)
        if (srow < 16) *(float4*)(As0 + (srow << 7) + scol) = S;
      } else {
        S = *(const float4*)(b0 + (size_t)srow * 2048 + scol);
        *(float4*)(As0 + (srow << 7) + scol) = S;
      }
    }
    __syncthreads();
    int cur = 0;
    for (int c = 0; c < nc; ++c) {
      if (c + 1 < nc) {
        const float* bn = chunk_base(c + 1);           // always 32-row h chunk
        S = *(const float4*)(bn + (size_t)srow * 2048 + scol);
      }
      const float* buf = cur ? As1 : As0;
      if (doL1 && c == 0)            consume_x(buf);
      else if (doL1 && c <= 8)       consume_dual(buf, (c - 1) << 5);
      else                           consume_w2(buf, (c - cL1) << 5);
      if (c + 1 < nc) {
        float* nbuf = cur ? As0 : As1;
        *(float4*)(nbuf + (srow << 7) + scol) = S;
        cur ^= 1;
      }
      __syncthreads();
    }

    // epilogues
    if (doL1) {
      float2 hv;
      #pragma unroll
      for (int m = 0; m < 2; ++m) {
        float iv = sigm(z1[m][0]), fv = sigm(z1[m][1]);
        float gv = tanhf(z1[m][2]), ov = sigm(z1[m][3]);
        c1[m] = fv * c1[m] + iv * gv;
        (&hv.x)[m] = ov * tanhf(c1[m]);
      }
      *(float2*)(pw + (size_t)jcol * 2048 + mgoff + (lane << 1)) = hv;
    }
    if (doL2) {
      float2 hv;
      #pragma unroll
      for (int m = 0; m < 2; ++m) {
        float iv = sigm(z2[m][0]), fv = sigm(z2[m][1]);
        float gv = tanhf(z2[m][2]), ov = sigm(z2[m][3]);
        c2[m] = fv * c2[m] + iv * gv;
        float h = ov * tanhf(c2[m]);
        pool[m] += h;
        (&hv.x)[m] = h;
      }
      *(float2*)(pw + (size_t)(256 + jcol) * 2048 + mgoff + (lane << 1)) = hv;
    }

    if (p < TSTEPS) mg_barrier(mybar, (unsigned)(p + 1) * 16u);
  }

  #pragma unroll
  for (int m = 0; m < 2; ++m)
    xg[(size_t)(mgoff + (lane << 1) + m) * 256 + jcol] = pool[m] * (1.0f / 50.0f);
}

// ---- GAT (verified R1-R9) ---------------------------------------------------
__global__ void __launch_bounds__(256)
gat_feat(const float* __restrict__ xin, const float* __restrict__ gW,
         const float* __restrict__ a_src, const float* __restrict__ a_dst,
         float* __restrict__ hfeat, float* __restrict__ es, float* __restrict__ ed)
{
  __shared__ float Xs[8][260];
  const int tid = threadIdx.x;
  const int r0 = blockIdx.x << 3;
  #pragma unroll
  for (int i = 0; i < 8; ++i) Xs[i][tid] = xin[((r0 + i) << 8) + tid];
  __syncthreads();
  float acc[8];
  #pragma unroll
  for (int i = 0; i < 8; ++i) acc[i] = 0.0f;
  for (int k = 0; k < 256; k += 4) {
    const float w0 = gW[(k + 0) * 256 + tid];
    const float w1 = gW[(k + 1) * 256 + tid];
    const float w2 = gW[(k + 2) * 256 + tid];
    const float w3 = gW[(k + 3) * 256 + tid];
    #pragma unroll
    for (int i = 0; i < 8; ++i)
      acc[i] += Xs[i][k] * w0 + Xs[i][k + 1] * w1 + Xs[i][k + 2] * w2 + Xs[i][k + 3] * w3;
  }
  const int h = tid >> 6;
  const int lane = tid & 63;
  const float asv = a_src[(h << 6) + lane];
  const float adv = a_dst[(h << 6) + lane];
  #pragma unroll
  for (int i = 0; i < 8; ++i) {
    hfeat[((r0 + i) << 8) + tid] = acc[i];
    float pse = acc[i] * asv;
    float pde = acc[i] * adv;
    #pragma unroll
    for (int off = 32; off > 0; off >>= 1) {
      pse += __shfl_down(pse, off);
      pde += __shfl_down(pde, off);
    }
    if (lane == 0) {
      es[((r0 + i) << 2) + h] = pse;
      ed[((r0 + i) << 2) + h] = pde;
    }
  }
}

__global__ void __launch_bounds__(256)
gat_out(const float* __restrict__ hfeat, const float* __restrict__ es, const float* __restrict__ ed,
        const float* __restrict__ gb, float* __restrict__ yout)
{
  __shared__ float exs[32][4];
  __shared__ float invden[4];
  const int tid = threadIdx.x;
  const int rbase = blockIdx.x << 5;
  if (tid < 128) {
    const int u = tid >> 2, h = tid & 3;
    float l = es[((rbase + u) << 2) + h] + ed[(rbase << 2) + h];
    exs[u][h] = (l < 0.0f) ? 0.2f * l : l;
  }
  __syncthreads();
  if (tid < 4) {
    const int h = tid;
    float m = -1e30f;
    for (int u = 0; u < 32; ++u) m = fmaxf(m, exs[u][h]);
    float s = 0.0f;
    for (int u = 0; u < 32; ++u) { float e = expf(exs[u][h] - m); exs[u][h] = e; s += e; }
    s += exs[0][h];                        // duplicate 0->0 edge
    invden[h] = 1.0f / (s + 1e-9f);
  }
  __syncthreads();
  const int h = tid >> 6;
  const float h0 = hfeat[(rbase << 8) + tid];
  float s = exs[0][h] * h0;
  for (int u = 0; u < 32; ++u)
    s += exs[u][h] * hfeat[((rbase + u) << 8) + tid];
  const float bias = gb[tid];
  const float inv1 = 1.0f / (1.0f + 1e-9f);
  yout[(rbase << 8) + tid] = gelu_t(s * invden[h] + bias);
  const float gv = gelu_t(h0 * inv1 + bias);
  for (int v = 1; v < 32; ++v)
    yout[((rbase + v) << 8) + tid] = gv;
}

// ---- launch -----------------------------------------------------------------
extern "C" void kernel_launch(void* const* d_in, const int* in_sizes, int n_in,
                              void* d_out, int out_size, void* d_ws, size_t ws_size,
                              hipStream_t stream) {
  (void)in_sizes; (void)n_in; (void)out_size; (void)ws_size;
  const float* states = (const float*)d_in[0];
  const float* Wx1 = (const float*)d_in[1];
  const float* Wh1 = (const float*)d_in[2];
  const float* b1  = (const float*)d_in[3];
  const float* Wx2 = (const float*)d_in[4];
  const float* Wh2 = (const float*)d_in[5];
  const float* b2  = (const float*)d_in[6];
  const float* gW1 = (const float*)d_in[7];
  const float* gas1 = (const float*)d_in[8];
  const float* gad1 = (const float*)d_in[9];
  const float* gb1 = (const float*)d_in[10];
  const float* gW2 = (const float*)d_in[11];
  const float* gas2 = (const float*)d_in[12];
  const float* gad2 = (const float*)d_in[13];
  const float* gb2 = (const float*)d_in[14];

  float* ws = (float*)d_ws;
  float* pair0 = ws;                       // 2*NB floats (h1|h2 plane)
  float* pair1 = ws + 2 * (size_t)NB;      // 2*NB floats
  float* xg    = ws + 4 * (size_t)NB;      // NB floats
  float* xT    = ws + 5 * (size_t)NB;      // 800*2048 floats
  float* Wp1   = xT + 800 * 2048;          // 256*272*4 = 278528
  float* Wp2   = Wp1 + 278528;             // 256*512*4 = 524288
  unsigned* bar = (unsigned*)(Wp2 + 524288);
  // GAT aliases (pair buffers dead after lstm)
  float* y1    = pair0;
  float* hfeat = pair0 + NB;
  float* es    = pair1;
  float* ed    = pair1 + 2048 * 4;
  float* dout  = (float*)d_out;

  pack_w<<<dim3(2048), dim3(256), 0, stream>>>(Wx1, Wh1, Wx2, Wh2, Wp1, Wp2, bar);
  transpose_x<<<dim3(32 * 13), dim3(256), 0, stream>>>(states, xT);

  void* args[] = { (void*)&xT, (void*)&Wp1, (void*)&Wp2, (void*)&b1, (void*)&b2,
                   (void*)&pair0, (void*)&pair1, (void*)&xg, (void*)&bar };
  hipError_t err = hipLaunchCooperativeKernel((void*)lstm_fused, dim3(256), dim3(1024),
                                              args, 0, stream);
  if (err != hipSuccess) {
    // Fallback: grid == 1 block/CU capacity, co-resident anyway. NEVER drop
    // the launch silently (R8: zero-output failure).
    lstm_fused<<<dim3(256), dim3(1024), 0, stream>>>(xT, Wp1, Wp2, b1, b2,
                                                     pair0, pair1, xg, bar);
  }

  gat_feat<<<dim3(256), dim3(256), 0, stream>>>(xg, gW1, gas1, gad1, hfeat, es, ed);
  gat_out<<<dim3(64), dim3(256), 0, stream>>>(hfeat, es, ed, gb1, y1);
  gat_feat<<<dim3(256), dim3(256), 0, stream>>>(y1, gW2, gas2, gad2, hfeat, es, ed);
  gat_out<<<dim3(64), dim3(256), 0, stream>>>(hfeat, es, ed, gb2, dout);
}

// Round 11
// 2724.347 us; speedup vs baseline: 4.4976x; 1.0739x over previous
//
#include <hip/hip_runtime.h>

#define TSTEPS 50
#define NB (2048 * 256)   // floats per h half-plane (256 rows x 2048 seqs)

__device__ __forceinline__ float sigm(float x) { return 1.0f / (1.0f + expf(-x)); }
__device__ __forceinline__ float gelu_t(float x) {
  float x3 = x * x * x;
  return 0.5f * x * (1.0f + tanhf(0.7978845608028654f * (x + 0.044715f * x3)));
}

// za[m][g] += a[m] * w[g]. Inline fn, not macro (macro param/member collisions R5,R7).
__device__ __forceinline__ void fma8(float (&za)[2][4], const float2 a, const float4 w) {
  za[0][0] += a.x * w.x; za[0][1] += a.x * w.y; za[0][2] += a.x * w.z; za[0][3] += a.x * w.w;
  za[1][0] += a.y * w.x; za[1][1] += a.y * w.y; za[1][2] += a.y * w.z; za[1][3] += a.y * w.w;
}

// m-group barrier (16 blocks). Plain __threadfence pair only (R4-proven; R6's
// buffer_inv was a 4.4GB disaster). No runtime-indexed local arrays (R9: 34GB).
__device__ __forceinline__ void mg_barrier(unsigned* bar, unsigned target) {
  __syncthreads();
  if (threadIdx.x == 0) {
    __threadfence();
    atomicAdd(bar, 1u);
    while (atomicAdd(bar, 0u) < target) __builtin_amdgcn_s_sleep(4);
    __threadfence();
  }
  __syncthreads();
}

// Pack W per-jcol streams: Wp1[jcol][k=0..271][4 gates], Wp2[jcol][k=0..511][4].
__global__ void __launch_bounds__(256)
pack_w(const float* __restrict__ Wx1, const float* __restrict__ Wh1,
       const float* __restrict__ Wx2, const float* __restrict__ Wh2,
       float* __restrict__ Wp1, float* __restrict__ Wp2, unsigned* __restrict__ bar) {
  const int idx = blockIdx.x * 256 + threadIdx.x;
  if (blockIdx.x == 0 && threadIdx.x < 256) bar[threadIdx.x] = 0u;
  if (idx < 256 * 272 * 4) {
    int g = idx & 3, k = (idx >> 2) % 272, jcol = idx / (272 * 4);
    int col = (g << 8) + jcol;
    Wp1[idx] = (k < 16) ? Wx1[(k << 10) + col] : Wh1[((k - 16) << 10) + col];
  }
  if (idx < 256 * 512 * 4) {
    int g = idx & 3, k = (idx >> 2) & 511, jcol = idx >> 11;
    int col = (g << 8) + jcol;
    Wp2[idx] = (k < 256) ? Wx2[(k << 10) + col] : Wh2[((k - 256) << 10) + col];
  }
}

// x[seq][t*16+d] -> xT[t*16+d][seq]
__global__ void __launch_bounds__(256)
transpose_x(const float* __restrict__ x, float* __restrict__ xT) {
  __shared__ float Ts[64][65];
  const int st = blockIdx.x & 31;
  const int tt = blockIdx.x >> 5;
  const int s0 = st << 6, t0 = tt << 6;
  const int r = threadIdx.x >> 6;
  const int c = threadIdx.x & 63;
  #pragma unroll
  for (int i = 0; i < 16; ++i) {
    int row = r + (i << 2);
    int td = t0 + c;
    if (td < 800) Ts[row][c] = x[(s0 + row) * 800 + td];
  }
  __syncthreads();
  #pragma unroll
  for (int i = 0; i < 16; ++i) {
    int row = r + (i << 2);
    int td = t0 + row;
    if (td < 800) xT[td * 2048 + s0 + c] = Ts[c][row];
  }
}

// Persistent fused 2-layer LSTM + time-mean pool.
// grid 256 = 16 mg (128 seqs) x 16 jg; block 1024 = 16 waves (4 waves/SIMD);
// wave wv owns jcol = jg*16+wv -> wave-uniform W (scalar s_load streams).
// 128-ROW LDS chunks (R11): 2x64KB h double-buffer + 8KB x buffer -> only
// ~6 barriers/phase (R10's 32-row chunks had ~19 -> barrier-stall bound).
// Chunk c (0..3) covers pair-plane rows c*128 (h1: c<2, h2: c>=2); the W2
// stream offset is the same c*128. Dual chunks (c<2, doL1) also feed z1 with
// W1h offset 16+c*128. All chunk addressing is ARITHMETIC (no local arrays).
__global__ void __launch_bounds__(1024, 1)
lstm_fused(const float* __restrict__ xT,
           const float* __restrict__ Wp1, const float* __restrict__ Wp2,
           const float* __restrict__ b1, const float* __restrict__ b2,
           float* __restrict__ pair0, float* __restrict__ pair1,
           float* __restrict__ xg, unsigned* __restrict__ bar)
{
  __shared__ float As0[128 * 128];         // 64KB
  __shared__ float As1[128 * 128];         // 64KB
  __shared__ float Asx[16 * 128];          // 8KB x chunk

  const int tid = threadIdx.x;
  const int lane = tid & 63;
  const int wv = __builtin_amdgcn_readfirstlane(tid >> 6);   // 0..15, uniform
  const int blk = blockIdx.x;
  const int mg = blk & 15, jg = blk >> 4;
  const int mgoff = mg << 7;               // 128 seqs
  const int jcol = (jg << 4) + wv;         // 0..255, wave-uniform
  unsigned* mybar = bar + (mg << 4);

  const float* wp1 = Wp1 + (size_t)jcol * (272 * 4);
  const float* wp2 = Wp2 + (size_t)jcol * (512 * 4);

  float4 zb1, zb2;
  #pragma unroll
  for (int g = 0; g < 4; ++g) {
    (&zb1.x)[g] = b1[(g << 8) + jcol];
    (&zb2.x)[g] = b2[(g << 8) + jcol];
  }

  float c1[2] = {0, 0}, c2[2] = {0, 0}, pool[2] = {0, 0};
  float z1[2][4], z2[2][4];

  const int srow = tid >> 5;               // 0..31
  const int scol = (tid & 31) << 2;        // 0..124 (floats)

  const int aoff = lane << 1;
  auto consume_x = [&]() {                           // 16 k-rows -> z1 (W1x)
    float2 Aq[4];
    #pragma unroll
    for (int i = 0; i < 4; ++i) Aq[i] = *(const float2*)(Asx + (i << 7) + aoff);
    #pragma unroll
    for (int k = 0; k < 16; ++k) {
      float2 a = Aq[k & 3];
      float4 w = *(const float4*)(wp1 + (k << 2));
      fma8(z1, a, w);
      int kn = k + 4; kn = kn > 15 ? 15 : kn;
      Aq[k & 3] = *(const float2*)(Asx + (kn << 7) + aoff);
    }
  };
  auto consume_dual = [&](const float* buf, int kk0) {  // 128 h1 rows -> z1,z2
    const float* w1b = wp1 + ((16 + kk0) << 2);
    const float* w2b = wp2 + (kk0 << 2);
    float2 Aq[4];
    #pragma unroll
    for (int i = 0; i < 4; ++i) Aq[i] = *(const float2*)(buf + (i << 7) + aoff);
    #pragma unroll 8
    for (int k = 0; k < 128; ++k) {
      float2 a = Aq[k & 3];
      float4 wva = *(const float4*)(w1b + (k << 2));
      float4 wvb = *(const float4*)(w2b + (k << 2));
      fma8(z1, a, wva);
      fma8(z2, a, wvb);
      int kn = k + 4; kn = kn > 127 ? 127 : kn;
      Aq[k & 3] = *(const float2*)(buf + (kn << 7) + aoff);
    }
  };
  auto consume_w2 = [&](const float* buf, int koff) {   // 128 rows -> z2 only
    const float* w2b = wp2 + (koff << 2);
    float2 Aq[4];
    #pragma unroll
    for (int i = 0; i < 4; ++i) Aq[i] = *(const float2*)(buf + (i << 7) + aoff);
    #pragma unroll 8
    for (int k = 0; k < 128; ++k) {
      float2 a = Aq[k & 3];
      float4 w = *(const float4*)(w2b + (k << 2));
      fma8(z2, a, w);
      int kn = k + 4; kn = kn > 127 ? 127 : kn;
      Aq[k & 3] = *(const float2*)(buf + (kn << 7) + aoff);
    }
  };

  for (int p = 0; p <= TSTEPS; ++p) {
    float* const pw = (p & 1) ? pair1 : pair0;
    const float* const prd = (p & 1) ? pair0 : pair1;
    const bool doL1 = (p < TSTEPS);
    const bool doL2 = (p >= 1);
    const bool doH2 = (p >= 2);
    const int nch = (doL2 ? 2 : 0) + (doH2 ? 2 : 0);   // 128-row h chunks
    const float* const xsrc = xT + (size_t)(p << 4) * 2048 + mgoff;

    if (doL1) {
      #pragma unroll
      for (int m = 0; m < 2; ++m) {
        z1[m][0] = zb1.x; z1[m][1] = zb1.y; z1[m][2] = zb1.z; z1[m][3] = zb1.w;
      }
    }
    if (doL2) {
      #pragma unroll
      for (int m = 0; m < 2; ++m) {
        z2[m][0] = zb2.x; z2[m][1] = zb2.y; z2[m][2] = zb2.z; z2[m][3] = zb2.w;
      }
    }

    // ---- stage x chunk (16 rows) and h chunk 0 (128 rows) together ----
    float4 Sx, S0, S1, S2, S3;
    if (doL1 && srow < 16) Sx = *(const float4*)(xsrc + (size_t)srow * 2048 + scol);
    if (doL2) {
      const float* b0 = prd + mgoff;       // chunk 0 = rows 0..127
      S0 = *(const float4*)(b0 + (size_t)(srow)        * 2048 + scol);
      S1 = *(const float4*)(b0 + (size_t)(srow + 32)   * 2048 + scol);
      S2 = *(const float4*)(b0 + (size_t)(srow + 64)   * 2048 + scol);
      S3 = *(const float4*)(b0 + (size_t)(srow + 96)   * 2048 + scol);
    }
    if (doL1 && srow < 16) *(float4*)(Asx + (srow << 7) + scol) = Sx;
    if (doL2) {
      *(float4*)(As0 + ((srow)       << 7) + scol) = S0;
      *(float4*)(As0 + ((srow + 32)  << 7) + scol) = S1;
      *(float4*)(As0 + ((srow + 64)  << 7) + scol) = S2;
      *(float4*)(As0 + ((srow + 96)  << 7) + scol) = S3;
    }
    __syncthreads();

    if (!doL2) {                           // p==0: only the x chunk
      consume_x();
    } else {
      int cur = 0;
      for (int c = 0; c < nch; ++c) {
        if (c + 1 < nch) {                 // T14: issue next chunk loads early
          const float* bn = prd + ((size_t)(c + 1) << 7) * 2048 + mgoff;
          S0 = *(const float4*)(bn + (size_t)(srow)      * 2048 + scol);
          S1 = *(const float4*)(bn + (size_t)(srow + 32) * 2048 + scol);
          S2 = *(const float4*)(bn + (size_t)(srow + 64) * 2048 + scol);
          S3 = *(const float4*)(bn + (size_t)(srow + 96) * 2048 + scol);
        }
        const float* buf = cur ? As1 : As0;
        if (doL1 && c == 0) consume_x();
        if (doL1 && c < 2)  consume_dual(buf, c << 7);
        else                consume_w2(buf, c << 7);
        if (c + 1 < nch) {
          float* nbuf = cur ? As0 : As1;
          *(float4*)(nbuf + ((srow)       << 7) + scol) = S0;
          *(float4*)(nbuf + ((srow + 32)  << 7) + scol) = S1;
          *(float4*)(nbuf + ((srow + 64)  << 7) + scol) = S2;
          *(float4*)(nbuf + ((srow + 96)  << 7) + scol) = S3;
          cur ^= 1;
        }
        __syncthreads();
      }
    }

    // epilogues
    if (doL1) {
      float2 hv;
      #pragma unroll
      for (int m = 0; m < 2; ++m) {
        float iv = sigm(z1[m][0]), fv = sigm(z1[m][1]);
        float gv = tanhf(z1[m][2]), ov = sigm(z1[m][3]);
        c1[m] = fv * c1[m] + iv * gv;
        (&hv.x)[m] = ov * tanhf(c1[m]);
      }
      *(float2*)(pw + (size_t)jcol * 2048 + mgoff + (lane << 1)) = hv;
    }
    if (doL2) {
      float2 hv;
      #pragma unroll
      for (int m = 0; m < 2; ++m) {
        float iv = sigm(z2[m][0]), fv = sigm(z2[m][1]);
        float gv = tanhf(z2[m][2]), ov = sigm(z2[m][3]);
        c2[m] = fv * c2[m] + iv * gv;
        float h = ov * tanhf(c2[m]);
        pool[m] += h;
        (&hv.x)[m] = h;
      }
      *(float2*)(pw + (size_t)(256 + jcol) * 2048 + mgoff + (lane << 1)) = hv;
    }

    if (p < TSTEPS) mg_barrier(mybar, (unsigned)(p + 1) * 16u);
  }

  #pragma unroll
  for (int m = 0; m < 2; ++m)
    xg[(size_t)(mgoff + (lane << 1) + m) * 256 + jcol] = pool[m] * (1.0f / 50.0f);
}

// ---- GAT (verified R1-R10) --------------------------------------------------
__global__ void __launch_bounds__(256)
gat_feat(const float* __restrict__ xin, const float* __restrict__ gW,
         const float* __restrict__ a_src, const float* __restrict__ a_dst,
         float* __restrict__ hfeat, float* __restrict__ es, float* __restrict__ ed)
{
  __shared__ float Xs[8][260];
  const int tid = threadIdx.x;
  const int r0 = blockIdx.x << 3;
  #pragma unroll
  for (int i = 0; i < 8; ++i) Xs[i][tid] = xin[((r0 + i) << 8) + tid];
  __syncthreads();
  float acc[8];
  #pragma unroll
  for (int i = 0; i < 8; ++i) acc[i] = 0.0f;
  for (int k = 0; k < 256; k += 4) {
    const float w0 = gW[(k + 0) * 256 + tid];
    const float w1 = gW[(k + 1) * 256 + tid];
    const float w2 = gW[(k + 2) * 256 + tid];
    const float w3 = gW[(k + 3) * 256 + tid];
    #pragma unroll
    for (int i = 0; i < 8; ++i)
      acc[i] += Xs[i][k] * w0 + Xs[i][k + 1] * w1 + Xs[i][k + 2] * w2 + Xs[i][k + 3] * w3;
  }
  const int h = tid >> 6;
  const int lane = tid & 63;
  const float asv = a_src[(h << 6) + lane];
  const float adv = a_dst[(h << 6) + lane];
  #pragma unroll
  for (int i = 0; i < 8; ++i) {
    hfeat[((r0 + i) << 8) + tid] = acc[i];
    float pse = acc[i] * asv;
    float pde = acc[i] * adv;
    #pragma unroll
    for (int off = 32; off > 0; off >>= 1) {
      pse += __shfl_down(pse, off);
      pde += __shfl_down(pde, off);
    }
    if (lane == 0) {
      es[((r0 + i) << 2) + h] = pse;
      ed[((r0 + i) << 2) + h] = pde;
    }
  }
}

__global__ void __launch_bounds__(256)
gat_out(const float* __restrict__ hfeat, const float* __restrict__ es, const float* __restrict__ ed,
        const float* __restrict__ gb, float* __restrict__ yout)
{
  __shared__ float exs[32][4];
  __shared__ float invden[4];
  const int tid = threadIdx.x;
  const int rbase = blockIdx.x << 5;
  if (tid < 128) {
    const int u = tid >> 2, h = tid & 3;
    float l = es[((rbase + u) << 2) + h] + ed[(rbase << 2) + h];
    exs[u][h] = (l < 0.0f) ? 0.2f * l : l;
  }
  __syncthreads();
  if (tid < 4) {
    const int h = tid;
    float m = -1e30f;
    for (int u = 0; u < 32; ++u) m = fmaxf(m, exs[u][h]);
    float s = 0.0f;
    for (int u = 0; u < 32; ++u) { float e = expf(exs[u][h] - m); exs[u][h] = e; s += e; }
    s += exs[0][h];                        // duplicate 0->0 edge
    invden[h] = 1.0f / (s + 1e-9f);
  }
  __syncthreads();
  const int h = tid >> 6;
  const float h0 = hfeat[(rbase << 8) + tid];
  float s = exs[0][h] * h0;
  for (int u = 0; u < 32; ++u)
    s += exs[u][h] * hfeat[((rbase + u) << 8) + tid];
  const float bias = gb[tid];
  const float inv1 = 1.0f / (1.0f + 1e-9f);
  yout[(rbase << 8) + tid] = gelu_t(s * invden[h] + bias);
  const float gv = gelu_t(h0 * inv1 + bias);
  for (int v = 1; v < 32; ++v)
    yout[((rbase + v) << 8) + tid] = gv;
}

// ---- launch -----------------------------------------------------------------
extern "C" void kernel_launch(void* const* d_in, const int* in_sizes, int n_in,
                              void* d_out, int out_size, void* d_ws, size_t ws_size,
                              hipStream_t stream) {
  (void)in_sizes; (void)n_in; (void)out_size; (void)ws_size;
  const float* states = (const float*)d_in[0];
  const float* Wx1 = (const float*)d_in[1];
  const float* Wh1 = (const float*)d_in[2];
  const float* b1  = (const float*)d_in[3];
  const float* Wx2 = (const float*)d_in[4];
  const float* Wh2 = (const float*)d_in[5];
  const float* b2  = (const float*)d_in[6];
  const float* gW1 = (const float*)d_in[7];
  const float* gas1 = (const float*)d_in[8];
  const float* gad1 = (const float*)d_in[9];
  const float* gb1 = (const float*)d_in[10];
  const float* gW2 = (const float*)d_in[11];
  const float* gas2 = (const float*)d_in[12];
  const float* gad2 = (const float*)d_in[13];
  const float* gb2 = (const float*)d_in[14];

  float* ws = (float*)d_ws;
  float* pair0 = ws;                       // 2*NB floats (h1|h2 plane)
  float* pair1 = ws + 2 * (size_t)NB;      // 2*NB floats
  float* xg    = ws + 4 * (size_t)NB;      // NB floats
  float* xT    = ws + 5 * (size_t)NB;      // 800*2048 floats
  float* Wp1   = xT + 800 * 2048;          // 256*272*4 = 278528
  float* Wp2   = Wp1 + 278528;             // 256*512*4 = 524288
  unsigned* bar = (unsigned*)(Wp2 + 524288);
  // GAT aliases (pair buffers dead after lstm)
  float* y1    = pair0;
  float* hfeat = pair0 + NB;
  float* es    = pair1;
  float* ed    = pair1 + 2048 * 4;
  float* dout  = (float*)d_out;

  pack_w<<<dim3(2048), dim3(256), 0, stream>>>(Wx1, Wh1, Wx2, Wh2, Wp1, Wp2, bar);
  transpose_x<<<dim3(32 * 13), dim3(256), 0, stream>>>(states, xT);

  void* args[] = { (void*)&xT, (void*)&Wp1, (void*)&Wp2, (void*)&b1, (void*)&b2,
                   (void*)&pair0, (void*)&pair1, (void*)&xg, (void*)&bar };
  hipError_t err = hipLaunchCooperativeKernel((void*)lstm_fused, dim3(256), dim3(1024),
                                              args, 0, stream);
  if (err != hipSuccess) {
    // Fallback: grid == 1 block/CU capacity, co-resident anyway. NEVER drop
    // the launch silently (R8: zero-output failure).
    lstm_fused<<<dim3(256), dim3(1024), 0, stream>>>(xT, Wp1, Wp2, b1, b2,
                                                     pair0, pair1, xg, bar);
  }

  gat_feat<<<dim3(256), dim3(256), 0, stream>>>(xg, gW1, gas1, gad1, hfeat, es, ed);
  gat_out<<<dim3(64), dim3(256), 0, stream>>>(hfeat, es, ed, gb1, y1);
  gat_feat<<<dim3(256), dim3(256), 0, stream>>>(y1, gW2, gas2, gad2, hfeat, es, ed);
  gat_out<<<dim3(64), dim3(256), 0, stream>>>(hfeat, es, ed, gb2, dout);
}